// Round 8
// baseline (296.904 us; speedup 1.0000x reference)
//
#include <hip/hip_runtime.h>

// Problem constants (fixed by the reference)
#define B_ 512
#define T_ 256
#define C_ 384
#define H_ 64
#define WT_STRIDE (H_ * C_)   // 24576 elements per matrix in WT scratch

typedef __bf16 bf16;
typedef bf16  bf16x8 __attribute__((ext_vector_type(8)));
typedef float f32x4  __attribute__((ext_vector_type(4)));

// ---------------- prep: W (fp32 [C][H]) -> WT (bf16 [mat][h][k]) ----------------
__global__ void prep_wt(const float* __restrict__ Wq,
                        const float* __restrict__ Wk,
                        const float* __restrict__ Wv,
                        bf16* __restrict__ wt)
{
    int idx = blockIdx.x * 256 + threadIdx.x;
    if (idx >= 3 * WT_STRIDE) return;
    int mat = idx / WT_STRIDE;
    int r   = idx % WT_STRIDE;
    int h   = r / C_;
    int k   = r % C_;
    const float* W = (mat == 0) ? Wq : (mat == 1) ? Wk : Wv;
    wt[idx] = (bf16)W[k * H_ + h];
}

__device__ __forceinline__ bf16x8 cvt8(float4 a, float4 b)
{
    bf16x8 r;
    r[0] = (bf16)a.x; r[1] = (bf16)a.y; r[2] = (bf16)a.z; r[3] = (bf16)a.w;
    r[4] = (bf16)b.x; r[5] = (bf16)b.y; r[6] = (bf16)b.z; r[7] = (bf16)b.w;
    return r;
}

// B-fragment: 8 consecutive k at fixed output column col (16B contiguous in wt).
template<int USE_WT>
__device__ __forceinline__ bf16x8 load_bfrag(const bf16* __restrict__ wt,
                                             const float* __restrict__ W,
                                             int mat, int col, int k)
{
    if (USE_WT) {
        return *reinterpret_cast<const bf16x8*>(wt + mat * WT_STRIDE + col * C_ + k);
    } else {
        bf16x8 r;
        const float* wp = W + k * H_ + col;
        #pragma unroll
        for (int j = 0; j < 8; ++j) r[j] = (bf16)wp[j * H_];
        return r;
    }
}

// XOR swizzle for k_s / vT_s / p_s: permute 8-elem (16B) chunks within a row.
#define SWZ(row, col) ((col) ^ (((row) & 7) << 3))

template<int USE_WT>
__global__ __launch_bounds__(512, 2)   // 2nd arg = min BLOCKS/CU (observed R2/R3) -> 16 waves/CU, 128-VGPR cap
void head_fused8(const float* __restrict__ x,
                 const float* __restrict__ Wq,
                 const float* __restrict__ Wk,
                 const float* __restrict__ Wv,
                 const bf16* __restrict__ wt,
                 float* __restrict__ out)
{
    // 32768 + 32768 + 16384 = 81920 B -> exactly 2 blocks per 160 KiB CU.
    // 2 blocks/CU is the point: block B's phase-1 HBM stream overlaps block
    // A's phase-2 compute (barriers only gate waves within a block).
    __shared__ bf16 k_s[T_ * 64];        // [t=256][h=64]  swizzled
    __shared__ bf16 vT_s[H_ * 256];      // [h=64][t=256]  swizzled
    __shared__ bf16 p_s[8 * 16 * 64];    // per-wave bounce (q then P), swizzled

    const int tid  = threadIdx.x;
    const int wave = tid >> 6;
    const int lane = tid & 63;
    const int lr   = lane & 15;
    const int lg   = lane >> 4;

    const int b = blockIdx.x;
    const float* xb = x + (size_t)b * T_ * C_;
    bf16* pw = &p_s[wave * 16 * 64];

    bf16x8 qf[2][2];   // q A-fragments, kept in regs for phase 2

    // ---------------- Phase 1: q,k,v projections (per-tile, fits 128 VGPR) ----------------
    #pragma unroll
    for (int p = 0; p < 2; ++p) {
        const int mt = p ? (15 - wave) : wave;
        f32x4 acc[3][4];   // q, k, v
        #pragma unroll
        for (int a = 0; a < 3; ++a)
            #pragma unroll
            for (int nw = 0; nw < 4; ++nw)
                acc[a][nw] = (f32x4){0.f, 0.f, 0.f, 0.f};

        #pragma unroll
        for (int half = 0; half < 2; ++half) {
            // ---- x: 12 float4 for this (tile, half) issued up front (MLP) ----
            const float* xr = xb + (mt * 16 + lr) * C_ + half * 192 + lg * 8;
            float4 t0[6], t1[6];
            #pragma unroll
            for (int ks = 0; ks < 6; ++ks) {
                t0[ks] = *reinterpret_cast<const float4*>(xr + ks * 32);
                t1[ks] = *reinterpret_cast<const float4*>(xr + ks * 32 + 4);
            }
            bf16x8 af[6];
            #pragma unroll
            for (int ks = 0; ks < 6; ++ks) af[ks] = cvt8(t0[ks], t1[ks]);

            // ---- consume: B-frags direct from L1/L2-resident wt ----
            #pragma unroll 2   // cap hoist window (R3 spill lesson)
            for (int ks = 0; ks < 6; ++ks) {
                const int k = half * 192 + ks * 32 + lg * 8;
                #pragma unroll
                for (int mat = 0; mat < 3; ++mat) {
                    #pragma unroll
                    for (int nw = 0; nw < 4; ++nw) {
                        bf16x8 bfr = load_bfrag<USE_WT>(wt, (mat == 0) ? Wq : (mat == 1) ? Wk : Wv,
                                                        mat, nw * 16 + lr, k);
                        acc[mat][nw] = __builtin_amdgcn_mfma_f32_16x16x32_bf16(
                            af[ks], bfr, acc[mat][nw], 0, 0, 0);
                    }
                }
            }
        }

        // D layout: row = lg*4+r (within tile), col = lr (within n-block)
        #pragma unroll
        for (int nw = 0; nw < 4; ++nw) {
            #pragma unroll
            for (int r = 0; r < 4; ++r) {
                int row = mt * 16 + lg * 4 + r;   // t
                int col = nw * 16 + lr;           // h
                k_s[row * 64 + SWZ(row, col)]   = (bf16)acc[1][nw][r];
                vT_s[col * 256 + SWZ(col, row)] = (bf16)acc[2][nw][r];
            }
        }
        // q: D-layout -> A-fragment layout via per-wave bounce, keep in regs
        #pragma unroll
        for (int nw = 0; nw < 4; ++nw) {
            #pragma unroll
            for (int r = 0; r < 4; ++r) {
                int row = lg * 4 + r;
                pw[row * 64 + SWZ(row, nw * 16 + lr)] = (bf16)acc[0][nw][r];
            }
        }
        asm volatile("s_waitcnt lgkmcnt(0)" ::: "memory");
        __builtin_amdgcn_sched_barrier(0);
        qf[p][0] = *reinterpret_cast<const bf16x8*>(&pw[lr * 64 + SWZ(lr, lg * 8)]);
        qf[p][1] = *reinterpret_cast<const bf16x8*>(&pw[lr * 64 + SWZ(lr, 32 + lg * 8)]);
        asm volatile("s_waitcnt lgkmcnt(0)" ::: "memory");
        __builtin_amdgcn_sched_barrier(0);   // reads land before next tile reuses pw
    }
    __syncthreads();   // k_s / vT_s complete

    // ---------------- Phase 2: causal attention, flash-style two halves ----------------
    const float scale = 0.051031036307982884f;   // 384^-0.5 (C, not H)

    #pragma unroll
    for (int p = 0; p < 2; ++p) {
        const int mt  = p ? (15 - wave) : wave;
        const int nkt = mt + 1;                   // valid key tiles

        float m[4], l[4];
        f32x4 oacc[4];
        #pragma unroll
        for (int r = 0; r < 4; ++r) { m[r] = -1e30f; l[r] = 0.f; }
        #pragma unroll
        for (int n = 0; n < 4; ++n) oacc[n] = (f32x4){0.f, 0.f, 0.f, 0.f};

        #pragma unroll
        for (int h = 0; h < 2; ++h) {
            const int vh = (nkt - h * 8) < 8 ? (nkt - h * 8) : 8;   // valid tiles in half
            if (vh > 0) {   // wave-uniform
                float s[8][4];
                #pragma unroll
                for (int j = 0; j < 8; ++j) {
                    const int kt = h * 8 + j;
                    if (j < vh) {   // wave-uniform
                        bf16x8 kf0 = *reinterpret_cast<const bf16x8*>(
                            &k_s[(kt * 16 + lr) * 64 + SWZ(lr, lg * 8)]);
                        bf16x8 kf1 = *reinterpret_cast<const bf16x8*>(
                            &k_s[(kt * 16 + lr) * 64 + SWZ(lr, 32 + lg * 8)]);
                        f32x4 sc = (f32x4){0.f, 0.f, 0.f, 0.f};
                        sc = __builtin_amdgcn_mfma_f32_16x16x32_bf16(qf[p][0], kf0, sc, 0, 0, 0);
                        sc = __builtin_amdgcn_mfma_f32_16x16x32_bf16(qf[p][1], kf1, sc, 0, 0, 0);
                        #pragma unroll
                        for (int r = 0; r < 4; ++r) {
                            float v = sc[r] * scale;
                            if (kt == mt && lr > lg * 4 + r) v = -1e30f;   // causal diag
                            s[j][r] = v;
                        }
                    } else {
                        #pragma unroll
                        for (int r = 0; r < 4; ++r) s[j][r] = -1e30f;
                    }
                }

                // per-row max of this half (row lg*4+r spans the 16 lanes of the group)
                float f[4];
                #pragma unroll
                for (int r = 0; r < 4; ++r) {
                    float pm = s[0][r];
                    #pragma unroll
                    for (int j = 1; j < 8; ++j) pm = fmaxf(pm, s[j][r]);
                    pm = fmaxf(pm, __shfl_xor(pm, 1));
                    pm = fmaxf(pm, __shfl_xor(pm, 2));
                    pm = fmaxf(pm, __shfl_xor(pm, 4));
                    pm = fmaxf(pm, __shfl_xor(pm, 8));
                    float nm = fmaxf(m[r], pm);
                    f[r] = __expf(m[r] - nm);   // rescale factor
                    m[r] = nm;
                    l[r] *= f[r];
                }
                #pragma unroll
                for (int n = 0; n < 4; ++n)
                    #pragma unroll
                    for (int r = 0; r < 4; ++r)
                        oacc[n][r] *= f[r];

                // exp + row sum
                #pragma unroll
                for (int r = 0; r < 4; ++r) {
                    float t = 0.f;
                    #pragma unroll
                    for (int j = 0; j < 8; ++j) {
                        float e = __expf(s[j][r] - m[r]);
                        s[j][r] = e;
                        t += e;
                    }
                    t += __shfl_xor(t, 1);
                    t += __shfl_xor(t, 2);
                    t += __shfl_xor(t, 4);
                    t += __shfl_xor(t, 8);
                    l[r] += t;
                }

                // PV (unnormalized P through the bounce)
                const int nkk = (vh + 1) >> 1;
                #pragma unroll
                for (int kkl = 0; kkl < 4; ++kkl) {
                    if (kkl < nkk) {   // wave-uniform
                        const int kk = h * 4 + kkl;
                        #pragma unroll
                        for (int r = 0; r < 4; ++r) {
                            int row = lg * 4 + r;
                            pw[row * 64 + SWZ(row, lr)]      = (bf16)s[2 * kkl][r];
                            pw[row * 64 + SWZ(row, 16 + lr)] = (bf16)s[2 * kkl + 1][r];
                        }
                        asm volatile("s_waitcnt lgkmcnt(0)" ::: "memory");
                        __builtin_amdgcn_sched_barrier(0);
                        bf16x8 pf = *reinterpret_cast<const bf16x8*>(
                            &pw[lr * 64 + SWZ(lr, lg * 8)]);
                        #pragma unroll
                        for (int n = 0; n < 4; ++n) {
                            bf16x8 vf = *reinterpret_cast<const bf16x8*>(
                                &vT_s[(n * 16 + lr) * 256 + SWZ(lr, kk * 32 + lg * 8)]);
                            oacc[n] = __builtin_amdgcn_mfma_f32_16x16x32_bf16(pf, vf, oacc[n], 0, 0, 0);
                        }
                    }
                }
            }
        }

        // epilogue: normalize by 1/l and store
        float rin[4];
        #pragma unroll
        for (int r = 0; r < 4; ++r) rin[r] = 1.0f / l[r];
        float* op = out + ((size_t)b * T_ + mt * 16) * H_;
        #pragma unroll
        for (int n = 0; n < 4; ++n)
            #pragma unroll
            for (int r = 0; r < 4; ++r)
                op[(lg * 4 + r) * H_ + n * 16 + lr] = oacc[n][r] * rin[r];
    }
}

extern "C" void kernel_launch(void* const* d_in, const int* in_sizes, int n_in,
                              void* d_out, int out_size, void* d_ws, size_t ws_size,
                              hipStream_t stream)
{
    (void)in_sizes; (void)n_in; (void)out_size;
    const float* x  = (const float*)d_in[0];
    const float* Wq = (const float*)d_in[1];
    const float* Wk = (const float*)d_in[2];
    const float* Wv = (const float*)d_in[3];
    float* o = (float*)d_out;

    if (ws_size >= (size_t)(3 * WT_STRIDE * sizeof(bf16))) {
        bf16* wt = (bf16*)d_ws;
        prep_wt<<<dim3((3 * WT_STRIDE + 255) / 256), dim3(256), 0, stream>>>(Wq, Wk, Wv, wt);
        head_fused8<1><<<dim3(B_), dim3(512), 0, stream>>>(x, Wq, Wk, Wv, wt, o);
    } else {
        head_fused8<0><<<dim3(B_), dim3(512), 0, stream>>>(x, Wq, Wk, Wv, nullptr, o);
    }
}

// Round 9
// 144.318 us; speedup vs baseline: 2.0573x; 2.0573x over previous
//
#include <hip/hip_runtime.h>

// Problem constants (fixed by the reference)
#define B_ 512
#define T_ 256
#define C_ 384
#define H_ 64

typedef __bf16 bf16;
typedef bf16  bf16x8 __attribute__((ext_vector_type(8)));
typedef bf16  bf16x4 __attribute__((ext_vector_type(4)));
typedef float f32x4  __attribute__((ext_vector_type(4)));

#define WT2_HALF  36864                      // elems per K-half in staged-order wt2
#define WT2_TOTAL (2 * WT2_HALF)             // 73728 elems = 147456 B
#define QKV_ELEMS (B_ * T_ * H_)             // 8388608 elems per tensor
// byte offsets in d_ws
#define Q_OFF  (1u << 20)
#define K_OFF  (Q_OFF + (unsigned)QKV_ELEMS * 2u)
#define V_OFF  (K_OFF + (unsigned)QKV_ELEMS * 2u)
#define WS_NEED ((size_t)V_OFF + (size_t)QKV_ELEMS * 2u)   // ~51.4 MB

// ---------------- prep: W (fp32 [C][H]) -> wt2 (bf16, STAGING order) ----------------
// wt2 holds 16B chunks in slot order s = mc*24 + (kkc^(mc&7)) so a LINEAR
// global_load_lds copy produces the swizzled wt_s image (pre-swizzled source).
__global__ void prep_wt2(const float* __restrict__ Wq,
                         const float* __restrict__ Wk,
                         const float* __restrict__ Wv,
                         bf16* __restrict__ wt2)
{
    int idx = blockIdx.x * 256 + threadIdx.x;
    if (idx >= WT2_TOTAL) return;
    int half = idx / WT2_HALF;
    int rem  = idx % WT2_HALF;
    int s    = rem >> 3;             // 16B chunk slot
    int e    = rem & 7;
    int mc   = s / 24;               // mat*64 + col
    int kkc  = (s % 24) ^ (mc & 7);  // inverse of slot swizzle
    int mat  = mc >> 6;
    int col  = mc & 63;
    int k    = half * 192 + kkc * 8 + e;
    const float* W = (mat == 0) ? Wq : (mat == 1) ? Wk : Wv;
    wt2[idx] = (bf16)W[k * H_ + col];
}

__device__ __forceinline__ bf16x8 cvt8(float4 a, float4 b)
{
    bf16x8 r;
    r[0] = (bf16)a.x; r[1] = (bf16)a.y; r[2] = (bf16)a.z; r[3] = (bf16)a.w;
    r[4] = (bf16)b.x; r[5] = (bf16)b.y; r[6] = (bf16)b.z; r[7] = (bf16)b.w;
    return r;
}

// direct HBM/L2 -> LDS, 16B per lane, wave-uniform LDS base + lane*16
__device__ __forceinline__ void gload_lds16(const bf16* g, bf16* l)
{
    __builtin_amdgcn_global_load_lds(
        (const __attribute__((address_space(1))) void*)g,
        (__attribute__((address_space(3))) void*)l,
        16, 0, 0);
}

// XOR swizzle for p_s: permute 8-elem (16B) chunks within a row by low row bits.
#define SWZ(row, col) ((col) ^ (((row) & 7) << 3))

// wt_s fragment address: [mc = mat*64+col][kk 0..191] bf16, 16B-chunk swizzled.
__device__ __forceinline__ const bf16x8* wts_frag(const bf16* wt_s, int mc, int kk)
{
    int byte = ((mc * 192 + kk) * 2) ^ ((mc & 7) << 4);
    return reinterpret_cast<const bf16x8*>(reinterpret_cast<const char*>(wt_s) + byte);
}

// =====================================================================
// Kernel A: projections. LDS = wt_s only (72KB) -> 2 blocks/CU, 4 waves/SIMD.
// Writes q,k row-major [b][t][64] and vT [b][64][256] (bf16) to workspace.
// =====================================================================
template<int USE_WT>
__global__ __launch_bounds__(512, 2)   // 2 blocks/CU -> VGPR cap 128 (R2/R3-observed semantics)
void proj_kernel(const float* __restrict__ x,
                 const float* __restrict__ Wq,
                 const float* __restrict__ Wk,
                 const float* __restrict__ Wv,
                 const bf16* __restrict__ wt2,
                 bf16* __restrict__ q_ws,
                 bf16* __restrict__ k_ws,
                 bf16* __restrict__ vT_ws)
{
    __shared__ bf16 wt_s[3 * 64 * 192];   // 73728 B, one K-half of all 3 mats

    const int tid  = threadIdx.x;
    const int wave = tid >> 6;
    const int lane = tid & 63;
    const int lr   = lane & 15;
    const int lg   = lane >> 4;

    const int b = blockIdx.x;
    const float* xb = x + (size_t)b * T_ * C_;
    const int mt0 = wave, mt1 = 15 - wave;

    f32x4 acc[2][3][4];   // [tile][q,k,v][nw] — live across halves (96 VGPR)
    #pragma unroll
    for (int t = 0; t < 2; ++t)
        #pragma unroll
        for (int a = 0; a < 3; ++a)
            #pragma unroll
            for (int nw = 0; nw < 4; ++nw)
                acc[t][a][nw] = (f32x4){0.f, 0.f, 0.f, 0.f};

    #pragma unroll 1
    for (int half = 0; half < 2; ++half) {
        if (half) __syncthreads();   // previous wt_s consumers done
        if (USE_WT) {
            #pragma unroll
            for (int c = 0; c < 9; ++c) {
                const bf16* g = wt2 + half * WT2_HALF + (c * 512 + tid) * 8;
                bf16* l = wt_s + (c * 512 + wave * 64) * 8;   // linear dest
                gload_lds16(g, l);
            }
        } else {
            #pragma unroll
            for (int c = 0; c < 9; ++c) {
                int f16 = c * 512 + tid;
                int mc  = f16 / 24;
                int kkc = f16 % 24;
                int mat = mc >> 6, col = mc & 63;
                const float* W = (mat == 0) ? Wq : (mat == 1) ? Wk : Wv;
                bf16x8 vv;
                #pragma unroll
                for (int j = 0; j < 8; ++j)
                    vv[j] = (bf16)W[(half * 192 + kkc * 8 + j) * H_ + col];
                int byte = ((mc * 192 + kkc * 8) * 2) ^ ((mc & 7) << 4);
                *reinterpret_cast<bf16x8*>(reinterpret_cast<char*>(wt_s) + byte) = vv;
            }
        }
        __syncthreads();   // wt_s ready (barrier drains vmcnt)

        const float* xr0 = xb + (mt0 * 16 + lr) * C_ + half * 192 + lg * 8;
        const float* xr1 = xb + (mt1 * 16 + lr) * C_ + half * 192 + lg * 8;
        #pragma unroll
        for (int ks = 0; ks < 6; ++ks) {
            float4 a0 = *reinterpret_cast<const float4*>(xr0 + ks * 32);
            float4 a1 = *reinterpret_cast<const float4*>(xr0 + ks * 32 + 4);
            float4 b0 = *reinterpret_cast<const float4*>(xr1 + ks * 32);
            float4 b1 = *reinterpret_cast<const float4*>(xr1 + ks * 32 + 4);
            bf16x8 af0 = cvt8(a0, a1);
            bf16x8 af1 = cvt8(b0, b1);
            const int kk = ks * 32 + lg * 8;
            #pragma unroll
            for (int mat = 0; mat < 3; ++mat) {
                #pragma unroll
                for (int nw = 0; nw < 4; ++nw) {
                    bf16x8 bfr = *wts_frag(wt_s, mat * 64 + nw * 16 + lr, kk);
                    acc[0][mat][nw] = __builtin_amdgcn_mfma_f32_16x16x32_bf16(
                        af0, bfr, acc[0][mat][nw], 0, 0, 0);
                    acc[1][mat][nw] = __builtin_amdgcn_mfma_f32_16x16x32_bf16(
                        af1, bfr, acc[1][mat][nw], 0, 0, 0);
                }
            }
        }
    }

    // ---- stores: q,k row-major scatter (b16); vT packed b64 (r contiguous in t) ----
    bf16* qb = q_ws  + (size_t)b * T_ * H_;
    bf16* kb = k_ws  + (size_t)b * T_ * H_;
    bf16* vb = vT_ws + (size_t)b * T_ * H_;   // [64][256]
    #pragma unroll
    for (int tile = 0; tile < 2; ++tile) {
        const int mt = tile ? mt1 : mt0;
        #pragma unroll
        for (int nw = 0; nw < 4; ++nw) {
            #pragma unroll
            for (int r = 0; r < 4; ++r) {
                int row = mt * 16 + lg * 4 + r;   // t
                int col = nw * 16 + lr;           // h
                qb[row * H_ + col] = (bf16)acc[tile][0][nw][r];
                kb[row * H_ + col] = (bf16)acc[tile][1][nw][r];
            }
            bf16x4 pv;
            #pragma unroll
            for (int r = 0; r < 4; ++r) pv[r] = (bf16)acc[tile][2][nw][r];
            *reinterpret_cast<bf16x4*>(vb + (nw * 16 + lr) * T_ + mt * 16 + lg * 4) = pv;
        }
    }
}

// =====================================================================
// Kernel B: causal attention. Fragments straight from L2/L3-resident qkv.
// LDS = per-wave P-bounce only (8KB). 256-thr blocks, 4 q-tiles/wave.
// =====================================================================
__global__ __launch_bounds__(256, 4)   // 4 blocks/CU -> VGPR cap 128
void attn_kernel(const bf16* __restrict__ q_ws,
                 const bf16* __restrict__ k_ws,
                 const bf16* __restrict__ vT_ws,
                 float* __restrict__ out)
{
    __shared__ bf16 p_s[4 * 16 * 64];   // per-wave bounce, swizzled

    const int tid  = threadIdx.x;
    const int wave = tid >> 6;
    const int lane = tid & 63;
    const int lr   = lane & 15;
    const int lg   = lane >> 4;

    const int b = blockIdx.x;
    const bf16* qb = q_ws  + (size_t)b * T_ * H_;
    const bf16* kb = k_ws  + (size_t)b * T_ * H_;
    const bf16* vb = vT_ws + (size_t)b * T_ * H_;
    bf16* pw = &p_s[wave * 16 * 64];

    const float scale = 0.051031036307982884f;   // 384^-0.5 (C, not H)

    #pragma unroll 1
    for (int p = 0; p < 4; ++p) {
        // balanced causal split: {w, 7-w, 8+w, 15-w} -> 34 kt-units each
        const int mt  = (p == 0) ? wave : (p == 1) ? 7 - wave
                      : (p == 2) ? 8 + wave : 15 - wave;
        const int nkt = mt + 1;

        bf16x8 qf0 = *reinterpret_cast<const bf16x8*>(qb + (mt * 16 + lr) * H_ + lg * 8);
        bf16x8 qf1 = *reinterpret_cast<const bf16x8*>(qb + (mt * 16 + lr) * H_ + 32 + lg * 8);

        float m[4], l[4];
        f32x4 oacc[4];
        #pragma unroll
        for (int r = 0; r < 4; ++r) { m[r] = -1e30f; l[r] = 0.f; }
        #pragma unroll
        for (int n = 0; n < 4; ++n) oacc[n] = (f32x4){0.f, 0.f, 0.f, 0.f};

        #pragma unroll
        for (int h = 0; h < 2; ++h) {
            const int vh = (nkt - h * 8) < 8 ? (nkt - h * 8) : 8;
            if (vh > 0) {   // wave-uniform
                float s[8][4];
                #pragma unroll
                for (int j = 0; j < 8; ++j) {
                    const int kt = h * 8 + j;
                    if (j < vh) {   // wave-uniform
                        bf16x8 kf0 = *reinterpret_cast<const bf16x8*>(
                            kb + (kt * 16 + lr) * H_ + lg * 8);
                        bf16x8 kf1 = *reinterpret_cast<const bf16x8*>(
                            kb + (kt * 16 + lr) * H_ + 32 + lg * 8);
                        f32x4 sc = (f32x4){0.f, 0.f, 0.f, 0.f};
                        sc = __builtin_amdgcn_mfma_f32_16x16x32_bf16(qf0, kf0, sc, 0, 0, 0);
                        sc = __builtin_amdgcn_mfma_f32_16x16x32_bf16(qf1, kf1, sc, 0, 0, 0);
                        #pragma unroll
                        for (int r = 0; r < 4; ++r) {
                            float v = sc[r] * scale;
                            if (kt == mt && lr > lg * 4 + r) v = -1e30f;   // causal diag
                            s[j][r] = v;
                        }
                    } else {
                        #pragma unroll
                        for (int r = 0; r < 4; ++r) s[j][r] = -1e30f;
                    }
                }

                float f[4];
                #pragma unroll
                for (int r = 0; r < 4; ++r) {
                    float pm = s[0][r];
                    #pragma unroll
                    for (int j = 1; j < 8; ++j) pm = fmaxf(pm, s[j][r]);
                    pm = fmaxf(pm, __shfl_xor(pm, 1));
                    pm = fmaxf(pm, __shfl_xor(pm, 2));
                    pm = fmaxf(pm, __shfl_xor(pm, 4));
                    pm = fmaxf(pm, __shfl_xor(pm, 8));
                    float nm = fmaxf(m[r], pm);
                    f[r] = __expf(m[r] - nm);
                    m[r] = nm;
                    l[r] *= f[r];
                }
                #pragma unroll
                for (int n = 0; n < 4; ++n)
                    #pragma unroll
                    for (int r = 0; r < 4; ++r)
                        oacc[n][r] *= f[r];

                #pragma unroll
                for (int r = 0; r < 4; ++r) {
                    float t = 0.f;
                    #pragma unroll
                    for (int j = 0; j < 8; ++j) {
                        float e = __expf(s[j][r] - m[r]);
                        s[j][r] = e;
                        t += e;
                    }
                    t += __shfl_xor(t, 1);
                    t += __shfl_xor(t, 2);
                    t += __shfl_xor(t, 4);
                    t += __shfl_xor(t, 8);
                    l[r] += t;
                }

                const int nkk = (vh + 1) >> 1;
                #pragma unroll
                for (int kkl = 0; kkl < 4; ++kkl) {
                    if (kkl < nkk) {   // wave-uniform
                        const int kk = h * 4 + kkl;
                        #pragma unroll
                        for (int r = 0; r < 4; ++r) {
                            int row = lg * 4 + r;
                            pw[row * 64 + SWZ(row, lr)]      = (bf16)s[2 * kkl][r];
                            pw[row * 64 + SWZ(row, 16 + lr)] = (bf16)s[2 * kkl + 1][r];
                        }
                        asm volatile("s_waitcnt lgkmcnt(0)" ::: "memory");
                        __builtin_amdgcn_sched_barrier(0);
                        bf16x8 pf = *reinterpret_cast<const bf16x8*>(
                            &pw[lr * 64 + SWZ(lr, lg * 8)]);
                        #pragma unroll
                        for (int n = 0; n < 4; ++n) {
                            bf16x8 vf = *reinterpret_cast<const bf16x8*>(
                                vb + (n * 16 + lr) * T_ + kk * 32 + lg * 8);
                            oacc[n] = __builtin_amdgcn_mfma_f32_16x16x32_bf16(pf, vf, oacc[n], 0, 0, 0);
                        }
                    }
                }
            }
        }

        float rin[4];
        #pragma unroll
        for (int r = 0; r < 4; ++r) rin[r] = 1.0f / l[r];
        float* op = out + ((size_t)b * T_ + mt * 16) * H_;
        #pragma unroll
        for (int n = 0; n < 4; ++n)
            #pragma unroll
            for (int r = 0; r < 4; ++r)
                op[(lg * 4 + r) * H_ + n * 16 + lr] = oacc[n][r] * rin[r];
    }
}

extern "C" void kernel_launch(void* const* d_in, const int* in_sizes, int n_in,
                              void* d_out, int out_size, void* d_ws, size_t ws_size,
                              hipStream_t stream)
{
    (void)in_sizes; (void)n_in; (void)out_size;
    const float* x  = (const float*)d_in[0];
    const float* Wq = (const float*)d_in[1];
    const float* Wk = (const float*)d_in[2];
    const float* Wv = (const float*)d_in[3];
    float* o = (float*)d_out;

    if (ws_size >= WS_NEED) {
        bf16* wt2  = (bf16*)d_ws;
        bf16* q_ws = (bf16*)((char*)d_ws + Q_OFF);
        bf16* k_ws = (bf16*)((char*)d_ws + K_OFF);
        bf16* v_ws = (bf16*)((char*)d_ws + V_OFF);
        prep_wt2<<<dim3((WT2_TOTAL + 255) / 256), dim3(256), 0, stream>>>(Wq, Wk, Wv, wt2);
        proj_kernel<1><<<dim3(B_), dim3(512), 0, stream>>>(x, Wq, Wk, Wv, wt2, q_ws, k_ws, v_ws);
        attn_kernel<<<dim3(B_), dim3(256), 0, stream>>>(q_ws, k_ws, v_ws, o);
    } else {
        // smaller ws: qkv at offset 0, W gathered from fp32 (no wt2)
        bf16* q_ws = (bf16*)d_ws;
        bf16* k_ws = q_ws + QKV_ELEMS;
        bf16* v_ws = k_ws + QKV_ELEMS;
        proj_kernel<0><<<dim3(B_), dim3(512), 0, stream>>>(x, Wq, Wk, Wv, nullptr, q_ws, k_ws, v_ws);
        attn_kernel<<<dim3(B_), dim3(256), 0, stream>>>(q_ws, k_ws, v_ws, o);
    }
}

// Round 10
// 83.549 us; speedup vs baseline: 3.5536x; 1.7273x over previous
//
#include <hip/hip_runtime.h>

// Problem constants (fixed by the reference)
#define B_ 512
#define T_ 256
#define C_ 384
#define H_ 64

typedef __bf16 bf16;
typedef bf16  bf16x8 __attribute__((ext_vector_type(8)));
typedef bf16  bf16x4 __attribute__((ext_vector_type(4)));
typedef float f32x4  __attribute__((ext_vector_type(4)));

#define WT2_HALF  36864                      // elems per K-half in staged-order wt2
#define WT2_TOTAL (2 * WT2_HALF)             // 73728 elems = 147456 B
#define QKV_ELEMS (B_ * T_ * H_)             // 8388608 elems per tensor
// byte offsets in d_ws
#define Q_OFF  (1u << 20)
#define K_OFF  (Q_OFF + (unsigned)QKV_ELEMS * 2u)
#define V_OFF  (K_OFF + (unsigned)QKV_ELEMS * 2u)
#define WS_NEED ((size_t)V_OFF + (size_t)QKV_ELEMS * 2u)   // ~51.4 MB

// ---------------- prep: W (fp32 [C][H]) -> wt2 (bf16, STAGING order) ----------------
__global__ void prep_wt2(const float* __restrict__ Wq,
                         const float* __restrict__ Wk,
                         const float* __restrict__ Wv,
                         bf16* __restrict__ wt2)
{
    int idx = blockIdx.x * 256 + threadIdx.x;
    if (idx >= WT2_TOTAL) return;
    int half = idx / WT2_HALF;
    int rem  = idx % WT2_HALF;
    int s    = rem >> 3;             // 16B chunk slot
    int e    = rem & 7;
    int mc   = s / 24;               // mat*64 + col
    int kkc  = (s % 24) ^ (mc & 7);  // inverse of slot swizzle
    int mat  = mc >> 6;
    int col  = mc & 63;
    int k    = half * 192 + kkc * 8 + e;
    const float* W = (mat == 0) ? Wq : (mat == 1) ? Wk : Wv;
    wt2[idx] = (bf16)W[k * H_ + col];
}

__device__ __forceinline__ bf16x8 cvt8(float4 a, float4 b)
{
    bf16x8 r;
    r[0] = (bf16)a.x; r[1] = (bf16)a.y; r[2] = (bf16)a.z; r[3] = (bf16)a.w;
    r[4] = (bf16)b.x; r[5] = (bf16)b.y; r[6] = (bf16)b.z; r[7] = (bf16)b.w;
    return r;
}

// direct HBM/L2 -> LDS, 16B per lane, wave-uniform LDS base + lane*16
__device__ __forceinline__ void gload_lds16(const bf16* g, bf16* l)
{
    __builtin_amdgcn_global_load_lds(
        (const __attribute__((address_space(1))) void*)g,
        (__attribute__((address_space(3))) void*)l,
        16, 0, 0);
}

// XOR swizzle: permute 8-elem (16B) chunks within a row by low row bits.
#define SWZ(row, col) ((col) ^ (((row) & 7) << 3))

// wt_s fragment address: [mc = mat*64+col][kk 0..191] bf16, 16B-chunk swizzled.
__device__ __forceinline__ const bf16x8* wts_frag(const bf16* wt_s, int mc, int kk)
{
    int byte = ((mc * 192 + kk) * 2) ^ ((mc & 7) << 4);
    return reinterpret_cast<const bf16x8*>(reinterpret_cast<const char*>(wt_s) + byte);
}

// =====================================================================
// Kernel A: projections. LDS = wt_s only (72KB) -> 2 blocks/CU, 4 waves/SIMD.
// Writes q row-major; k and vT in the PRE-SWIZZLED LDS-image layout so the
// attention kernel can stage them with a linear global_load_lds copy.
// =====================================================================
template<int USE_WT>
__global__ __launch_bounds__(512, 2)   // 2 blocks/CU -> VGPR cap 128
void proj_kernel(const float* __restrict__ x,
                 const float* __restrict__ Wq,
                 const float* __restrict__ Wk,
                 const float* __restrict__ Wv,
                 const bf16* __restrict__ wt2,
                 bf16* __restrict__ q_ws,
                 bf16* __restrict__ k_ws,
                 bf16* __restrict__ vT_ws)
{
    __shared__ bf16 wt_s[3 * 64 * 192];   // 73728 B, one K-half of all 3 mats

    const int tid  = threadIdx.x;
    const int wave = tid >> 6;
    const int lane = tid & 63;
    const int lr   = lane & 15;
    const int lg   = lane >> 4;

    const int b = blockIdx.x;
    const float* xb = x + (size_t)b * T_ * C_;
    const int mt0 = wave, mt1 = 15 - wave;

    f32x4 acc[2][3][4];   // [tile][q,k,v][nw] — live across halves (96 VGPR)
    #pragma unroll
    for (int t = 0; t < 2; ++t)
        #pragma unroll
        for (int a = 0; a < 3; ++a)
            #pragma unroll
            for (int nw = 0; nw < 4; ++nw)
                acc[t][a][nw] = (f32x4){0.f, 0.f, 0.f, 0.f};

    #pragma unroll 1
    for (int half = 0; half < 2; ++half) {
        if (half) __syncthreads();   // previous wt_s consumers done
        if (USE_WT) {
            #pragma unroll
            for (int c = 0; c < 9; ++c) {
                const bf16* g = wt2 + half * WT2_HALF + (c * 512 + tid) * 8;
                bf16* l = wt_s + (c * 512 + wave * 64) * 8;   // linear dest
                gload_lds16(g, l);
            }
        } else {
            #pragma unroll
            for (int c = 0; c < 9; ++c) {
                int f16 = c * 512 + tid;
                int mc  = f16 / 24;
                int kkc = f16 % 24;
                int mat = mc >> 6, col = mc & 63;
                const float* W = (mat == 0) ? Wq : (mat == 1) ? Wk : Wv;
                bf16x8 vv;
                #pragma unroll
                for (int j = 0; j < 8; ++j)
                    vv[j] = (bf16)W[(half * 192 + kkc * 8 + j) * H_ + col];
                int byte = ((mc * 192 + kkc * 8) * 2) ^ ((mc & 7) << 4);
                *reinterpret_cast<bf16x8*>(reinterpret_cast<char*>(wt_s) + byte) = vv;
            }
        }
        __syncthreads();   // wt_s ready (barrier drains vmcnt)

        const float* xr0 = xb + (mt0 * 16 + lr) * C_ + half * 192 + lg * 8;
        const float* xr1 = xb + (mt1 * 16 + lr) * C_ + half * 192 + lg * 8;
        #pragma unroll
        for (int ks = 0; ks < 6; ++ks) {
            float4 a0 = *reinterpret_cast<const float4*>(xr0 + ks * 32);
            float4 a1 = *reinterpret_cast<const float4*>(xr0 + ks * 32 + 4);
            float4 b0 = *reinterpret_cast<const float4*>(xr1 + ks * 32);
            float4 b1 = *reinterpret_cast<const float4*>(xr1 + ks * 32 + 4);
            bf16x8 af0 = cvt8(a0, a1);
            bf16x8 af1 = cvt8(b0, b1);
            const int kk = ks * 32 + lg * 8;
            #pragma unroll
            for (int mat = 0; mat < 3; ++mat) {
                #pragma unroll
                for (int nw = 0; nw < 4; ++nw) {
                    bf16x8 bfr = *wts_frag(wt_s, mat * 64 + nw * 16 + lr, kk);
                    acc[0][mat][nw] = __builtin_amdgcn_mfma_f32_16x16x32_bf16(
                        af0, bfr, acc[0][mat][nw], 0, 0, 0);
                    acc[1][mat][nw] = __builtin_amdgcn_mfma_f32_16x16x32_bf16(
                        af1, bfr, acc[1][mat][nw], 0, 0, 0);
                }
            }
        }
    }

    // ---- stores: q row-major; k,vT in pre-swizzled LDS-image layouts ----
    bf16* qb = q_ws  + (size_t)b * T_ * H_;
    bf16* kb = k_ws  + (size_t)b * T_ * H_;   // image of k_s [t][h] swizzled
    bf16* vb = vT_ws + (size_t)b * T_ * H_;   // image of vT_s [h][t] swizzled
    #pragma unroll
    for (int tile = 0; tile < 2; ++tile) {
        const int mt = tile ? mt1 : mt0;
        #pragma unroll
        for (int nw = 0; nw < 4; ++nw) {
            #pragma unroll
            for (int r = 0; r < 4; ++r) {
                int row = mt * 16 + lg * 4 + r;   // t
                int col = nw * 16 + lr;           // h
                qb[row * H_ + col]              = (bf16)acc[tile][0][nw][r];
                kb[row * 64 + SWZ(row, col)]    = (bf16)acc[tile][1][nw][r];
            }
            // vT: 4 consecutive t at column h; XOR moves the 8-chunk, keeps 4-group
            int col = nw * 16 + lr;
            int t0  = (mt * 16 + lg * 4) ^ ((col & 7) << 3);
            bf16x4 pv;
            #pragma unroll
            for (int r = 0; r < 4; ++r) pv[r] = (bf16)acc[tile][2][nw][r];
            *reinterpret_cast<bf16x4*>(vb + col * 256 + t0) = pv;
        }
    }
}

// =====================================================================
// Kernel B: causal attention. k_s/vT_s staged via linear global_load_lds
// (pre-swizzled by producer). LDS = 32+32+16 = 80KB -> 2 blocks/CU,
// 16 waves/CU (4/SIMD — double the fused kernel's occupancy).
// =====================================================================
__global__ __launch_bounds__(512, 2)
void attn_kernel(const bf16* __restrict__ q_ws,
                 const bf16* __restrict__ k_ws,
                 const bf16* __restrict__ vT_ws,
                 float* __restrict__ out)
{
    __shared__ bf16 k_s[T_ * 64];        // [t][h] swizzled (16384 el)
    __shared__ bf16 vT_s[H_ * 256];      // [h][t] swizzled (16384 el)
    __shared__ bf16 p_s[8 * 16 * 64];    // per-wave bounce (8192 el)

    const int tid  = threadIdx.x;
    const int wave = tid >> 6;
    const int lane = tid & 63;
    const int lr   = lane & 15;
    const int lg   = lane >> 4;

    const int b = blockIdx.x;
    const bf16* qb = q_ws + (size_t)b * T_ * H_;
    bf16* pw = &p_s[wave * 16 * 64];

    // ---- stage k_s and vT_s: linear 16B copies (4+4 per thread) ----
    {
        const bf16* kg = k_ws  + (size_t)b * T_ * H_;
        const bf16* vg = vT_ws + (size_t)b * T_ * H_;
        #pragma unroll
        for (int c = 0; c < 4; ++c)
            gload_lds16(kg + (c * 512 + tid) * 8, k_s + (c * 512 + wave * 64) * 8);
        #pragma unroll
        for (int c = 0; c < 4; ++c)
            gload_lds16(vg + (c * 512 + tid) * 8, vT_s + (c * 512 + wave * 64) * 8);
    }
    __syncthreads();   // staging complete (barrier drains vmcnt)

    const float scale = 0.051031036307982884f;   // 384^-0.5 (C, not H)

    #pragma unroll
    for (int p = 0; p < 2; ++p) {
        const int mt  = p ? (15 - wave) : wave;   // balanced: 17 kt-units/wave
        const int nkt = mt + 1;

        bf16x8 qf0 = *reinterpret_cast<const bf16x8*>(qb + (mt * 16 + lr) * H_ + lg * 8);
        bf16x8 qf1 = *reinterpret_cast<const bf16x8*>(qb + (mt * 16 + lr) * H_ + 32 + lg * 8);

        float m[4], l[4];
        f32x4 oacc[4];
        #pragma unroll
        for (int r = 0; r < 4; ++r) { m[r] = -1e30f; l[r] = 0.f; }
        #pragma unroll
        for (int n = 0; n < 4; ++n) oacc[n] = (f32x4){0.f, 0.f, 0.f, 0.f};

        #pragma unroll
        for (int h = 0; h < 2; ++h) {
            const int vh = (nkt - h * 8) < 8 ? (nkt - h * 8) : 8;
            if (vh > 0) {   // wave-uniform
                float s[8][4];
                #pragma unroll
                for (int j = 0; j < 8; ++j) {
                    const int kt = h * 8 + j;
                    if (j < vh) {   // wave-uniform
                        bf16x8 kf0 = *reinterpret_cast<const bf16x8*>(
                            &k_s[(kt * 16 + lr) * 64 + SWZ(lr, lg * 8)]);
                        bf16x8 kf1 = *reinterpret_cast<const bf16x8*>(
                            &k_s[(kt * 16 + lr) * 64 + SWZ(lr, 32 + lg * 8)]);
                        f32x4 sc = (f32x4){0.f, 0.f, 0.f, 0.f};
                        sc = __builtin_amdgcn_mfma_f32_16x16x32_bf16(qf0, kf0, sc, 0, 0, 0);
                        sc = __builtin_amdgcn_mfma_f32_16x16x32_bf16(qf1, kf1, sc, 0, 0, 0);
                        #pragma unroll
                        for (int r = 0; r < 4; ++r) {
                            float v = sc[r] * scale;
                            if (kt == mt && lr > lg * 4 + r) v = -1e30f;   // causal diag
                            s[j][r] = v;
                        }
                    } else {
                        #pragma unroll
                        for (int r = 0; r < 4; ++r) s[j][r] = -1e30f;
                    }
                }

                float f[4];
                #pragma unroll
                for (int r = 0; r < 4; ++r) {
                    float pm = s[0][r];
                    #pragma unroll
                    for (int j = 1; j < 8; ++j) pm = fmaxf(pm, s[j][r]);
                    pm = fmaxf(pm, __shfl_xor(pm, 1));
                    pm = fmaxf(pm, __shfl_xor(pm, 2));
                    pm = fmaxf(pm, __shfl_xor(pm, 4));
                    pm = fmaxf(pm, __shfl_xor(pm, 8));
                    float nm = fmaxf(m[r], pm);
                    f[r] = __expf(m[r] - nm);
                    m[r] = nm;
                    l[r] *= f[r];
                }
                #pragma unroll
                for (int n = 0; n < 4; ++n)
                    #pragma unroll
                    for (int r = 0; r < 4; ++r)
                        oacc[n][r] *= f[r];

                #pragma unroll
                for (int r = 0; r < 4; ++r) {
                    float t = 0.f;
                    #pragma unroll
                    for (int j = 0; j < 8; ++j) {
                        float e = __expf(s[j][r] - m[r]);
                        s[j][r] = e;
                        t += e;
                    }
                    t += __shfl_xor(t, 1);
                    t += __shfl_xor(t, 2);
                    t += __shfl_xor(t, 4);
                    t += __shfl_xor(t, 8);
                    l[r] += t;
                }

                const int nkk = (vh + 1) >> 1;
                #pragma unroll
                for (int kkl = 0; kkl < 4; ++kkl) {
                    if (kkl < nkk) {   // wave-uniform
                        const int kk = h * 4 + kkl;
                        #pragma unroll
                        for (int r = 0; r < 4; ++r) {
                            int row = lg * 4 + r;
                            pw[row * 64 + SWZ(row, lr)]      = (bf16)s[2 * kkl][r];
                            pw[row * 64 + SWZ(row, 16 + lr)] = (bf16)s[2 * kkl + 1][r];
                        }
                        asm volatile("s_waitcnt lgkmcnt(0)" ::: "memory");
                        __builtin_amdgcn_sched_barrier(0);
                        bf16x8 pf = *reinterpret_cast<const bf16x8*>(
                            &pw[lr * 64 + SWZ(lr, lg * 8)]);
                        #pragma unroll
                        for (int n = 0; n < 4; ++n) {
                            bf16x8 vf = *reinterpret_cast<const bf16x8*>(
                                &vT_s[(n * 16 + lr) * 256 + SWZ(lr, kk * 32 + lg * 8)]);
                            oacc[n] = __builtin_amdgcn_mfma_f32_16x16x32_bf16(pf, vf, oacc[n], 0, 0, 0);
                        }
                    }
                }
            }
        }

        float rin[4];
        #pragma unroll
        for (int r = 0; r < 4; ++r) rin[r] = 1.0f / l[r];
        float* op = out + ((size_t)b * T_ + mt * 16) * H_;
        #pragma unroll
        for (int n = 0; n < 4; ++n)
            #pragma unroll
            for (int r = 0; r < 4; ++r)
                op[(lg * 4 + r) * H_ + n * 16 + lr] = oacc[n][r] * rin[r];
    }
}

extern "C" void kernel_launch(void* const* d_in, const int* in_sizes, int n_in,
                              void* d_out, int out_size, void* d_ws, size_t ws_size,
                              hipStream_t stream)
{
    (void)in_sizes; (void)n_in; (void)out_size;
    const float* x  = (const float*)d_in[0];
    const float* Wq = (const float*)d_in[1];
    const float* Wk = (const float*)d_in[2];
    const float* Wv = (const float*)d_in[3];
    float* o = (float*)d_out;

    if (ws_size >= WS_NEED) {
        bf16* wt2  = (bf16*)d_ws;
        bf16* q_ws = (bf16*)((char*)d_ws + Q_OFF);
        bf16* k_ws = (bf16*)((char*)d_ws + K_OFF);
        bf16* v_ws = (bf16*)((char*)d_ws + V_OFF);
        prep_wt2<<<dim3((WT2_TOTAL + 255) / 256), dim3(256), 0, stream>>>(Wq, Wk, Wv, wt2);
        proj_kernel<1><<<dim3(B_), dim3(512), 0, stream>>>(x, Wq, Wk, Wv, wt2, q_ws, k_ws, v_ws);
        attn_kernel<<<dim3(B_), dim3(512), 0, stream>>>(q_ws, k_ws, v_ws, o);
    } else {
        bf16* q_ws = (bf16*)d_ws;
        bf16* k_ws = q_ws + QKV_ELEMS;
        bf16* v_ws = k_ws + QKV_ELEMS;
        proj_kernel<0><<<dim3(B_), dim3(512), 0, stream>>>(x, Wq, Wk, Wv, nullptr, q_ws, k_ws, v_ws);
        attn_kernel<<<dim3(B_), dim3(512), 0, stream>>>(q_ws, k_ws, v_ws, o);
    }
}

// Round 11
// 66.849 us; speedup vs baseline: 4.4414x; 1.2498x over previous
//
#include <hip/hip_runtime.h>

// Problem constants (fixed by the reference)
#define B_ 512
#define T_ 256
#define C_ 384
#define H_ 64

typedef __bf16 bf16;
typedef bf16  bf16x8 __attribute__((ext_vector_type(8)));
typedef float f32x4  __attribute__((ext_vector_type(4)));

#define NCHUNK     3
#define CHUNK_K    128
#define WT3_CHUNK  24576                  // elems per K-chunk (3*64*128)
#define WT3_TOTAL  (NCHUNK * WT3_CHUNK)   // 73728 elems = 147456 B

// ---------------- prep: W (fp32 [C][H]) -> wt3 (bf16, STAGING order) ----------------
// wt3 holds 16B chunks in slot order s = mc*16 + (kkc^(mc&7)) per K-chunk, so a
// LINEAR global_load_lds copy produces the swizzled wt_s image.
__global__ void prep_wt3(const float* __restrict__ Wq,
                         const float* __restrict__ Wk,
                         const float* __restrict__ Wv,
                         bf16* __restrict__ wt3)
{
    int idx = blockIdx.x * 256 + threadIdx.x;
    if (idx >= WT3_TOTAL) return;
    int chunk = idx / WT3_CHUNK;
    int rem   = idx % WT3_CHUNK;
    int s     = rem >> 3;              // 16B chunk slot 0..3071
    int e     = rem & 7;
    int mc    = s >> 4;                // mat*64 + col (16 slots per row)
    int kkc   = (s & 15) ^ (mc & 7);   // inverse of slot swizzle
    int mat   = mc >> 6;
    int col   = mc & 63;
    int k     = chunk * CHUNK_K + kkc * 8 + e;
    const float* W = (mat == 0) ? Wq : (mat == 1) ? Wk : Wv;
    wt3[idx] = (bf16)W[k * H_ + col];
}

__device__ __forceinline__ bf16x8 cvt8(float4 a, float4 b)
{
    bf16x8 r;
    r[0] = (bf16)a.x; r[1] = (bf16)a.y; r[2] = (bf16)a.z; r[3] = (bf16)a.w;
    r[4] = (bf16)b.x; r[5] = (bf16)b.y; r[6] = (bf16)b.z; r[7] = (bf16)b.w;
    return r;
}

// direct HBM/L2 -> LDS, 16B per lane, wave-uniform LDS base + lane*16
__device__ __forceinline__ void gload_lds16(const bf16* g, bf16* l)
{
    __builtin_amdgcn_global_load_lds(
        (const __attribute__((address_space(1))) void*)g,
        (__attribute__((address_space(3))) void*)l,
        16, 0, 0);
}

// XOR swizzle for k_s / vT_s / p_s: permute 8-elem (16B) chunks within a row.
#define SWZ(row, col) ((col) ^ (((row) & 7) << 3))

// wt_s fragment address: [mc = mat*64+col][kk 0..127] bf16, 16B-chunk swizzled.
// Read bank check: 2 lanes/bank-group max (free, m136).
__device__ __forceinline__ const bf16x8* wts_frag(const bf16* wt_s, int mc, int kk)
{
    int byte = ((mc * CHUNK_K + kk) * 2) ^ ((mc & 7) << 4);
    return reinterpret_cast<const bf16x8*>(reinterpret_cast<const char*>(wt_s) + byte);
}

// =====================================================================
// Fused kernel, LDS-union edition:
//   phase 1 uses wt_s (48KB, aliased)   } union = 64KB
//   phase 2 uses k_s+vT_s (64KB, aliased)}
//   + p_s 16KB  => exactly 80KB => 2 blocks/CU, 4 waves/SIMD (R10's
//   occupancy without R10's 100MB qkv round-trip).
// =====================================================================
template<int USE_WT>
__global__ __launch_bounds__(512, 2)   // 2 blocks/CU -> VGPR cap 128 (observed semantics)
void head_fused11(const float* __restrict__ x,
                  const float* __restrict__ Wq,
                  const float* __restrict__ Wk,
                  const float* __restrict__ Wv,
                  const bf16* __restrict__ wt3,
                  float* __restrict__ out)
{
    __shared__ bf16 lds_u[32768];       // 64KB union
    __shared__ bf16 p_s[8 * 16 * 64];   // 16KB per-wave bounce (q then P)

    bf16* wt_s = lds_u;                 // phase-1 view: 24576 elems used
    bf16* k_s  = lds_u;                 // phase-2 view: [t=256][h=64] swizzled
    bf16* vT_s = lds_u + 16384;         // phase-2 view: [h=64][t=256] swizzled

    const int tid  = threadIdx.x;
    const int wave = tid >> 6;
    const int lane = tid & 63;
    const int lr   = lane & 15;
    const int lg   = lane >> 4;

    const int b = blockIdx.x;
    const float* xb = x + (size_t)b * T_ * C_;
    bf16* pw = &p_s[wave * 16 * 64];

    const int mt0 = wave, mt1 = 15 - wave;
    bf16x8 qf[2][2];   // q A-fragments, kept in regs for phase 2

    // ---------------- Phase 1: q,k,v projections (x read ONCE) ----------------
    f32x4 acc[2][3][4];   // [tile][q,k,v][nw] — 96 VGPRs, live across chunks
    #pragma unroll
    for (int t = 0; t < 2; ++t)
        #pragma unroll
        for (int a = 0; a < 3; ++a)
            #pragma unroll
            for (int nw = 0; nw < 4; ++nw)
                acc[t][a][nw] = (f32x4){0.f, 0.f, 0.f, 0.f};

    #pragma unroll 1
    for (int chunk = 0; chunk < NCHUNK; ++chunk) {
        if (chunk) __syncthreads();   // previous wt_s consumers done
        // ---- stage wt_s: 3072 16B chunks over 512 threads = 6 each ----
        if (USE_WT) {
            #pragma unroll
            for (int c = 0; c < 6; ++c) {
                const bf16* g = wt3 + chunk * WT3_CHUNK + (c * 512 + tid) * 8;
                bf16* l = wt_s + (c * 512 + wave * 64) * 8;   // linear dest
                gload_lds16(g, l);
            }
        } else {
            #pragma unroll
            for (int c = 0; c < 6; ++c) {
                int f16 = c * 512 + tid;       // slot 0..3071
                int mc  = f16 >> 4;
                int kkc = f16 & 15;
                int mat = mc >> 6, col = mc & 63;
                const float* W = (mat == 0) ? Wq : (mat == 1) ? Wk : Wv;
                bf16x8 vv;
                #pragma unroll
                for (int j = 0; j < 8; ++j)
                    vv[j] = (bf16)W[(chunk * CHUNK_K + kkc * 8 + j) * H_ + col];
                int byte = ((mc * CHUNK_K + kkc * 8) * 2) ^ ((mc & 7) << 4);
                *reinterpret_cast<bf16x8*>(reinterpret_cast<char*>(wt_s) + byte) = vv;
            }
        }
        __syncthreads();   // wt_s ready (barrier drains vmcnt)

        const float* xr0 = xb + (mt0 * 16 + lr) * C_ + chunk * CHUNK_K + lg * 8;
        const float* xr1 = xb + (mt1 * 16 + lr) * C_ + chunk * CHUNK_K + lg * 8;
        #pragma unroll
        for (int ks = 0; ks < 4; ++ks) {
            float4 a0 = *reinterpret_cast<const float4*>(xr0 + ks * 32);
            float4 a1 = *reinterpret_cast<const float4*>(xr0 + ks * 32 + 4);
            float4 b0 = *reinterpret_cast<const float4*>(xr1 + ks * 32);
            float4 b1 = *reinterpret_cast<const float4*>(xr1 + ks * 32 + 4);
            bf16x8 af0 = cvt8(a0, a1);
            bf16x8 af1 = cvt8(b0, b1);
            const int kk = ks * 32 + lg * 8;
            #pragma unroll
            for (int mat = 0; mat < 3; ++mat) {
                #pragma unroll
                for (int nw = 0; nw < 4; ++nw) {
                    bf16x8 bfr = *wts_frag(wt_s, mat * 64 + nw * 16 + lr, kk);
                    acc[0][mat][nw] = __builtin_amdgcn_mfma_f32_16x16x32_bf16(
                        af0, bfr, acc[0][mat][nw], 0, 0, 0);
                    acc[1][mat][nw] = __builtin_amdgcn_mfma_f32_16x16x32_bf16(
                        af1, bfr, acc[1][mat][nw], 0, 0, 0);
                }
            }
        }
    }
    __syncthreads();   // ALL waves done with wt_s -> union may be overwritten

    // ---- epilogue: k/vT into the union, q through per-wave bounce ----
    #pragma unroll
    for (int tile = 0; tile < 2; ++tile) {
        const int mt = tile ? mt1 : mt0;
        #pragma unroll
        for (int nw = 0; nw < 4; ++nw) {
            #pragma unroll
            for (int r = 0; r < 4; ++r) {
                int row = mt * 16 + lg * 4 + r;   // t
                int col = nw * 16 + lr;           // h
                k_s[row * 64 + SWZ(row, col)]   = (bf16)acc[tile][1][nw][r];
                vT_s[col * 256 + SWZ(col, row)] = (bf16)acc[tile][2][nw][r];
            }
        }
        #pragma unroll
        for (int nw = 0; nw < 4; ++nw) {
            #pragma unroll
            for (int r = 0; r < 4; ++r) {
                int row = lg * 4 + r;
                pw[row * 64 + SWZ(row, nw * 16 + lr)] = (bf16)acc[tile][0][nw][r];
            }
        }
        asm volatile("s_waitcnt lgkmcnt(0)" ::: "memory");
        __builtin_amdgcn_sched_barrier(0);
        qf[tile][0] = *reinterpret_cast<const bf16x8*>(&pw[lr * 64 + SWZ(lr, lg * 8)]);
        qf[tile][1] = *reinterpret_cast<const bf16x8*>(&pw[lr * 64 + SWZ(lr, 32 + lg * 8)]);
        asm volatile("s_waitcnt lgkmcnt(0)" ::: "memory");
        __builtin_amdgcn_sched_barrier(0);   // reads land before next tile reuses pw
    }
    __syncthreads();   // k_s / vT_s complete

    // ---------------- Phase 2: causal attention, flash-style two halves ----------------
    const float scale = 0.051031036307982884f;   // 384^-0.5 (C, not H)

    #pragma unroll
    for (int p = 0; p < 2; ++p) {
        const int mt  = p ? mt1 : mt0;
        const int nkt = mt + 1;                   // valid key tiles

        float m[4], l[4];
        f32x4 oacc[4];
        #pragma unroll
        for (int r = 0; r < 4; ++r) { m[r] = -1e30f; l[r] = 0.f; }
        #pragma unroll
        for (int n = 0; n < 4; ++n) oacc[n] = (f32x4){0.f, 0.f, 0.f, 0.f};

        #pragma unroll
        for (int h = 0; h < 2; ++h) {
            const int vh = (nkt - h * 8) < 8 ? (nkt - h * 8) : 8;   // valid tiles in half
            if (vh > 0) {   // wave-uniform
                float s[8][4];
                #pragma unroll
                for (int j = 0; j < 8; ++j) {
                    const int kt = h * 8 + j;
                    if (j < vh) {   // wave-uniform
                        bf16x8 kf0 = *reinterpret_cast<const bf16x8*>(
                            &k_s[(kt * 16 + lr) * 64 + SWZ(lr, lg * 8)]);
                        bf16x8 kf1 = *reinterpret_cast<const bf16x8*>(
                            &k_s[(kt * 16 + lr) * 64 + SWZ(lr, 32 + lg * 8)]);
                        f32x4 sc = (f32x4){0.f, 0.f, 0.f, 0.f};
                        sc = __builtin_amdgcn_mfma_f32_16x16x32_bf16(qf[p][0], kf0, sc, 0, 0, 0);
                        sc = __builtin_amdgcn_mfma_f32_16x16x32_bf16(qf[p][1], kf1, sc, 0, 0, 0);
                        #pragma unroll
                        for (int r = 0; r < 4; ++r) {
                            float v = sc[r] * scale;
                            if (kt == mt && lr > lg * 4 + r) v = -1e30f;   // causal diag
                            s[j][r] = v;
                        }
                    } else {
                        #pragma unroll
                        for (int r = 0; r < 4; ++r) s[j][r] = -1e30f;
                    }
                }

                // per-row max of this half (row lg*4+r spans the 16 lanes of the group)
                float f[4];
                #pragma unroll
                for (int r = 0; r < 4; ++r) {
                    float pm = s[0][r];
                    #pragma unroll
                    for (int j = 1; j < 8; ++j) pm = fmaxf(pm, s[j][r]);
                    pm = fmaxf(pm, __shfl_xor(pm, 1));
                    pm = fmaxf(pm, __shfl_xor(pm, 2));
                    pm = fmaxf(pm, __shfl_xor(pm, 4));
                    pm = fmaxf(pm, __shfl_xor(pm, 8));
                    float nm = fmaxf(m[r], pm);
                    f[r] = __expf(m[r] - nm);   // rescale factor
                    m[r] = nm;
                    l[r] *= f[r];
                }
                #pragma unroll
                for (int n = 0; n < 4; ++n)
                    #pragma unroll
                    for (int r = 0; r < 4; ++r)
                        oacc[n][r] *= f[r];

                // exp + row sum
                #pragma unroll
                for (int r = 0; r < 4; ++r) {
                    float t = 0.f;
                    #pragma unroll
                    for (int j = 0; j < 8; ++j) {
                        float e = __expf(s[j][r] - m[r]);
                        s[j][r] = e;
                        t += e;
                    }
                    t += __shfl_xor(t, 1);
                    t += __shfl_xor(t, 2);
                    t += __shfl_xor(t, 4);
                    t += __shfl_xor(t, 8);
                    l[r] += t;
                }

                // PV (unnormalized P through the bounce)
                const int nkk = (vh + 1) >> 1;
                #pragma unroll
                for (int kkl = 0; kkl < 4; ++kkl) {
                    if (kkl < nkk) {   // wave-uniform
                        const int kk = h * 4 + kkl;
                        #pragma unroll
                        for (int r = 0; r < 4; ++r) {
                            int row = lg * 4 + r;
                            pw[row * 64 + SWZ(row, lr)]      = (bf16)s[2 * kkl][r];
                            pw[row * 64 + SWZ(row, 16 + lr)] = (bf16)s[2 * kkl + 1][r];
                        }
                        asm volatile("s_waitcnt lgkmcnt(0)" ::: "memory");
                        __builtin_amdgcn_sched_barrier(0);
                        bf16x8 pf = *reinterpret_cast<const bf16x8*>(
                            &pw[lr * 64 + SWZ(lr, lg * 8)]);
                        #pragma unroll
                        for (int n = 0; n < 4; ++n) {
                            bf16x8 vf = *reinterpret_cast<const bf16x8*>(
                                &vT_s[(n * 16 + lr) * 256 + SWZ(lr, kk * 32 + lg * 8)]);
                            oacc[n] = __builtin_amdgcn_mfma_f32_16x16x32_bf16(pf, vf, oacc[n], 0, 0, 0);
                        }
                    }
                }
            }
        }

        // epilogue: normalize by 1/l and store
        float rin[4];
        #pragma unroll
        for (int r = 0; r < 4; ++r) rin[r] = 1.0f / l[r];
        float* op = out + ((size_t)b * T_ + mt * 16) * H_;
        #pragma unroll
        for (int n = 0; n < 4; ++n)
            #pragma unroll
            for (int r = 0; r < 4; ++r)
                op[(lg * 4 + r) * H_ + n * 16 + lr] = oacc[n][r] * rin[r];
    }
}

extern "C" void kernel_launch(void* const* d_in, const int* in_sizes, int n_in,
                              void* d_out, int out_size, void* d_ws, size_t ws_size,
                              hipStream_t stream)
{
    (void)in_sizes; (void)n_in; (void)out_size;
    const float* x  = (const float*)d_in[0];
    const float* Wq = (const float*)d_in[1];
    const float* Wk = (const float*)d_in[2];
    const float* Wv = (const float*)d_in[3];
    float* o = (float*)d_out;

    if (ws_size >= (size_t)(WT3_TOTAL * sizeof(bf16))) {
        bf16* wt3 = (bf16*)d_ws;
        prep_wt3<<<dim3((WT3_TOTAL + 255) / 256), dim3(256), 0, stream>>>(Wq, Wk, Wv, wt3);
        head_fused11<1><<<dim3(B_), dim3(512), 0, stream>>>(x, Wq, Wk, Wv, wt3, o);
    } else {
        head_fused11<0><<<dim3(B_), dim3(512), 0, stream>>>(x, Wq, Wk, Wv, nullptr, o);
    }
}

// Round 12
// 64.912 us; speedup vs baseline: 4.5739x; 1.0298x over previous
//
#include <hip/hip_runtime.h>

// Problem constants (fixed by the reference)
#define B_ 512
#define T_ 256
#define C_ 384
#define H_ 64

typedef __bf16 bf16;
typedef bf16  bf16x8 __attribute__((ext_vector_type(8)));
typedef bf16  bf16x2 __attribute__((ext_vector_type(2)));
typedef float f32x4  __attribute__((ext_vector_type(4)));
typedef int   i32x4  __attribute__((ext_vector_type(4)));

#define NCHUNK     3
#define CHUNK_K    128
#define WT3_CHUNK  24576                  // elems per K-chunk (3*64*128)
#define WT3_TOTAL  (NCHUNK * WT3_CHUNK)   // 73728 elems = 147456 B

// ---------------- prep: W (fp32 [C][H]) -> wt3 (bf16, STAGING order) ----------------
__global__ void prep_wt3(const float* __restrict__ Wq,
                         const float* __restrict__ Wk,
                         const float* __restrict__ Wv,
                         bf16* __restrict__ wt3)
{
    int idx = blockIdx.x * 256 + threadIdx.x;
    if (idx >= WT3_TOTAL) return;
    int chunk = idx / WT3_CHUNK;
    int rem   = idx % WT3_CHUNK;
    int s     = rem >> 3;              // 16B chunk slot 0..3071
    int e     = rem & 7;
    int mc    = s >> 4;                // mat*64 + col (16 slots per row)
    int kkc   = (s & 15) ^ (mc & 7);   // inverse of slot swizzle
    int mat   = mc >> 6;
    int col   = mc & 63;
    int k     = chunk * CHUNK_K + kkc * 8 + e;
    const float* W = (mat == 0) ? Wq : (mat == 1) ? Wk : Wv;
    wt3[idx] = (bf16)W[k * H_ + col];
}

__device__ __forceinline__ bf16x8 cvt8(float4 a, float4 b)
{
    bf16x8 r;
    r[0] = (bf16)a.x; r[1] = (bf16)a.y; r[2] = (bf16)a.z; r[3] = (bf16)a.w;
    r[4] = (bf16)b.x; r[5] = (bf16)b.y; r[6] = (bf16)b.z; r[7] = (bf16)b.w;
    return r;
}

__device__ __forceinline__ unsigned pack2(float a, float b)
{
    bf16x2 v; v[0] = (bf16)a; v[1] = (bf16)b;
    return __builtin_bit_cast(unsigned, v);
}

// direct HBM/L2 -> LDS, 16B per lane, wave-uniform LDS base + lane*16
__device__ __forceinline__ void gload_lds16(const bf16* g, bf16* l)
{
    __builtin_amdgcn_global_load_lds(
        (const __attribute__((address_space(1))) void*)g,
        (__attribute__((address_space(3))) void*)l,
        16, 0, 0);
}

// XOR swizzle for k_s / vT_s / p_s: permute 8-elem (16B) chunks within a row.
#define SWZ(row, col) ((col) ^ (((row) & 7) << 3))

// wt_s fragment address: [mc = mat*64+col][kk 0..127] bf16, 16B-chunk swizzled.
__device__ __forceinline__ const bf16x8* wts_frag(const bf16* wt_s, int mc, int kk)
{
    int byte = ((mc * CHUNK_K + kk) * 2) ^ ((mc & 7) << 4);
    return reinterpret_cast<const bf16x8*>(reinterpret_cast<const char*>(wt_s) + byte);
}

// =====================================================================
// Fused kernel: LDS-union (80KB -> 2 blocks/CU) + swapped-QK^T phase 2
// (lane-local softmax rows, shuffle-assembled P, no PV LDS bounce).
// =====================================================================
template<int USE_WT>
__global__ __launch_bounds__(512, 2)
void head_fused12(const float* __restrict__ x,
                  const float* __restrict__ Wq,
                  const float* __restrict__ Wk,
                  const float* __restrict__ Wv,
                  const bf16* __restrict__ wt3,
                  float* __restrict__ out)
{
    __shared__ bf16 lds_u[32768];       // 64KB union
    __shared__ bf16 p_s[8 * 16 * 64];   // 16KB per-wave bounce (q transpose only)

    bf16* wt_s = lds_u;                 // phase-1 view
    bf16* k_s  = lds_u;                 // phase-2 view: [t=256][h=64] swizzled
    bf16* vT_s = lds_u + 16384;         // phase-2 view: [h=64][t=256] swizzled

    const int tid  = threadIdx.x;
    const int wave = tid >> 6;
    const int lane = tid & 63;
    const int lr   = lane & 15;
    const int lg   = lane >> 4;

    const int b = blockIdx.x;
    const float* xb = x + (size_t)b * T_ * C_;
    bf16* pw = &p_s[wave * 16 * 64];

    const int mt0 = wave, mt1 = 15 - wave;
    bf16x8 qf[2][2];   // q fragments (same layout works as A or B operand)

    // ---------------- Phase 1: q,k,v projections (x read ONCE) ----------------
    f32x4 acc[2][3][4];   // [tile][q,k,v][nw]
    #pragma unroll
    for (int t = 0; t < 2; ++t)
        #pragma unroll
        for (int a = 0; a < 3; ++a)
            #pragma unroll
            for (int nw = 0; nw < 4; ++nw)
                acc[t][a][nw] = (f32x4){0.f, 0.f, 0.f, 0.f};

    #pragma unroll 1
    for (int chunk = 0; chunk < NCHUNK; ++chunk) {
        if (chunk) __syncthreads();   // previous wt_s consumers done
        if (USE_WT) {
            #pragma unroll
            for (int c = 0; c < 6; ++c) {
                const bf16* g = wt3 + chunk * WT3_CHUNK + (c * 512 + tid) * 8;
                bf16* l = wt_s + (c * 512 + wave * 64) * 8;   // linear dest
                gload_lds16(g, l);
            }
        } else {
            #pragma unroll
            for (int c = 0; c < 6; ++c) {
                int f16 = c * 512 + tid;       // slot 0..3071
                int mc  = f16 >> 4;
                int kkc = f16 & 15;
                int mat = mc >> 6, col = mc & 63;
                const float* W = (mat == 0) ? Wq : (mat == 1) ? Wk : Wv;
                bf16x8 vv;
                #pragma unroll
                for (int j = 0; j < 8; ++j)
                    vv[j] = (bf16)W[(chunk * CHUNK_K + kkc * 8 + j) * H_ + col];
                int byte = ((mc * CHUNK_K + kkc * 8) * 2) ^ ((mc & 7) << 4);
                *reinterpret_cast<bf16x8*>(reinterpret_cast<char*>(wt_s) + byte) = vv;
            }
        }
        __syncthreads();   // wt_s ready (barrier drains vmcnt)

        const float* xr0 = xb + (mt0 * 16 + lr) * C_ + chunk * CHUNK_K + lg * 8;
        const float* xr1 = xb + (mt1 * 16 + lr) * C_ + chunk * CHUNK_K + lg * 8;
        #pragma unroll
        for (int ks = 0; ks < 4; ++ks) {
            float4 a0 = *reinterpret_cast<const float4*>(xr0 + ks * 32);
            float4 a1 = *reinterpret_cast<const float4*>(xr0 + ks * 32 + 4);
            float4 b0 = *reinterpret_cast<const float4*>(xr1 + ks * 32);
            float4 b1 = *reinterpret_cast<const float4*>(xr1 + ks * 32 + 4);
            bf16x8 af0 = cvt8(a0, a1);
            bf16x8 af1 = cvt8(b0, b1);
            const int kk = ks * 32 + lg * 8;
            #pragma unroll
            for (int mat = 0; mat < 3; ++mat) {
                #pragma unroll
                for (int nw = 0; nw < 4; ++nw) {
                    bf16x8 bfr = *wts_frag(wt_s, mat * 64 + nw * 16 + lr, kk);
                    acc[0][mat][nw] = __builtin_amdgcn_mfma_f32_16x16x32_bf16(
                        af0, bfr, acc[0][mat][nw], 0, 0, 0);
                    acc[1][mat][nw] = __builtin_amdgcn_mfma_f32_16x16x32_bf16(
                        af1, bfr, acc[1][mat][nw], 0, 0, 0);
                }
            }
        }
    }
    __syncthreads();   // ALL waves done with wt_s -> union may be overwritten

    // ---- epilogue: k/vT into the union, q through per-wave bounce ----
    #pragma unroll
    for (int tile = 0; tile < 2; ++tile) {
        const int mt = tile ? mt1 : mt0;
        #pragma unroll
        for (int nw = 0; nw < 4; ++nw) {
            #pragma unroll
            for (int r = 0; r < 4; ++r) {
                int row = mt * 16 + lg * 4 + r;   // t
                int col = nw * 16 + lr;           // h
                k_s[row * 64 + SWZ(row, col)]   = (bf16)acc[tile][1][nw][r];
                vT_s[col * 256 + SWZ(col, row)] = (bf16)acc[tile][2][nw][r];
            }
        }
        #pragma unroll
        for (int nw = 0; nw < 4; ++nw) {
            #pragma unroll
            for (int r = 0; r < 4; ++r) {
                int row = lg * 4 + r;
                pw[row * 64 + SWZ(row, nw * 16 + lr)] = (bf16)acc[tile][0][nw][r];
            }
        }
        asm volatile("s_waitcnt lgkmcnt(0)" ::: "memory");
        __builtin_amdgcn_sched_barrier(0);
        qf[tile][0] = *reinterpret_cast<const bf16x8*>(&pw[lr * 64 + SWZ(lr, lg * 8)]);
        qf[tile][1] = *reinterpret_cast<const bf16x8*>(&pw[lr * 64 + SWZ(lr, 32 + lg * 8)]);
        asm volatile("s_waitcnt lgkmcnt(0)" ::: "memory");
        __builtin_amdgcn_sched_barrier(0);   // reads land before next tile reuses pw
    }
    __syncthreads();   // k_s / vT_s complete

    // ---------------- Phase 2: swapped QK^T causal attention ----------------
    // sc = mfma(K, Q): D[k_local][q] -> lane lr OWNS row q=lr; s[kt][r] =
    // P[q=lr][t=kt*16+lg*4+r]. Softmax stats are lane-scalar (reduce over lg
    // = shfl_xor 16,32). PV computes out^T = V^T . P^T with P B-frags
    // assembled by register shuffles (no LDS bounce).
    const float scale = 0.051031036307982884f;   // 384^-0.5 (C, not H)

    #pragma unroll
    for (int p = 0; p < 2; ++p) {
        const int mt  = p ? mt1 : mt0;
        const int nkt = mt + 1;                   // valid key tiles

        float m = -1e30f, l = 0.f;
        f32x4 oacc[4];
        #pragma unroll
        for (int n = 0; n < 4; ++n) oacc[n] = (f32x4){0.f, 0.f, 0.f, 0.f};

        #pragma unroll
        for (int h = 0; h < 2; ++h) {
            const int vh = (nkt - h * 8) < 8 ? (nkt - h * 8) : 8;   // valid tiles in half
            if (vh > 0) {   // wave-uniform
                float s[8][4];
                #pragma unroll
                for (int j = 0; j < 8; ++j) {
                    const int kt = h * 8 + j;
                    if (j < vh) {   // wave-uniform
                        bf16x8 kf0 = *reinterpret_cast<const bf16x8*>(
                            &k_s[(kt * 16 + lr) * 64 + SWZ(lr, lg * 8)]);
                        bf16x8 kf1 = *reinterpret_cast<const bf16x8*>(
                            &k_s[(kt * 16 + lr) * 64 + SWZ(lr, 32 + lg * 8)]);
                        f32x4 sc = (f32x4){0.f, 0.f, 0.f, 0.f};
                        sc = __builtin_amdgcn_mfma_f32_16x16x32_bf16(kf0, qf[p][0], sc, 0, 0, 0);
                        sc = __builtin_amdgcn_mfma_f32_16x16x32_bf16(kf1, qf[p][1], sc, 0, 0, 0);
                        #pragma unroll
                        for (int r = 0; r < 4; ++r) {
                            float v = sc[r] * scale;
                            // diag tile: t_local = lg*4+r, q = lr; mask t > q
                            if (kt == mt && (lg * 4 + r) > lr) v = -1e30f;
                            s[j][r] = v;
                        }
                    } else {
                        #pragma unroll
                        for (int r = 0; r < 4; ++r) s[j][r] = -1e30f;
                    }
                }

                // ---- softmax stats: row q=lr is lane-local + lg-spread ----
                float pm = s[0][0];
                #pragma unroll
                for (int j = 0; j < 8; ++j)
                    #pragma unroll
                    for (int r = 0; r < 4; ++r) pm = fmaxf(pm, s[j][r]);
                pm = fmaxf(pm, __shfl_xor(pm, 16));
                pm = fmaxf(pm, __shfl_xor(pm, 32));
                float nm = fmaxf(m, pm);
                float fr = __expf(m - nm);   // 0 on first valid half
                m = nm;
                l *= fr;
                #pragma unroll
                for (int n = 0; n < 4; ++n)
                    #pragma unroll
                    for (int r = 0; r < 4; ++r) oacc[n][r] *= fr;

                float tt = 0.f;
                #pragma unroll
                for (int j = 0; j < 8; ++j)
                    #pragma unroll
                    for (int r = 0; r < 4; ++r) {
                        float e = __expf(s[j][r] - m);
                        s[j][r] = e;
                        tt += e;
                    }
                tt += __shfl_xor(tt, 16);
                tt += __shfl_xor(tt, 32);
                l += tt;

                // ---- PV: out^T = V^T . P^T; P B-frag via register shuffles ----
                const int nkk = (vh + 1) >> 1;
                #pragma unroll
                for (int kkl = 0; kkl < 4; ++kkl) {
                    if (kkl < nkk) {   // wave-uniform
                        const int kk = h * 4 + kkl;
                        // source packs: this lane's P (bf16 pairs) for tiles 2kkl, 2kkl+1
                        unsigned lo0 = pack2(s[2*kkl][0],   s[2*kkl][1]);
                        unsigned hi0 = pack2(s[2*kkl][2],   s[2*kkl][3]);
                        unsigned lo1 = pack2(s[2*kkl+1][0], s[2*kkl+1][1]);
                        unsigned hi1 = pack2(s[2*kkl+1][2], s[2*kkl+1][3]);
                        // target lane (lr,lg), elem j: t = kk*32 + lg*8 + j
                        //   src lane = (lg&1)*32 + (j>>2)*16 + lr, tile = lg>>1, r = j&3
                        const int src0 = (lg & 1) * 32 + lr;
                        const int src1 = src0 + 16;
                        const bool t1  = (lg >> 1) != 0;
                        int a0 = __shfl((int)lo0, src0), a1 = __shfl((int)lo1, src0);
                        unsigned w0 = t1 ? (unsigned)a1 : (unsigned)a0;
                        int b0 = __shfl((int)hi0, src0), b1 = __shfl((int)hi1, src0);
                        unsigned w1 = t1 ? (unsigned)b1 : (unsigned)b0;
                        int c0 = __shfl((int)lo0, src1), c1 = __shfl((int)lo1, src1);
                        unsigned w2 = t1 ? (unsigned)c1 : (unsigned)c0;
                        int d0 = __shfl((int)hi0, src1), d1 = __shfl((int)hi1, src1);
                        unsigned w3 = t1 ? (unsigned)d1 : (unsigned)d0;
                        i32x4 wi = {(int)w0, (int)w1, (int)w2, (int)w3};
                        bf16x8 pf = __builtin_bit_cast(bf16x8, wi);
                        #pragma unroll
                        for (int n = 0; n < 4; ++n) {
                            bf16x8 vf = *reinterpret_cast<const bf16x8*>(
                                &vT_s[(n * 16 + lr) * 256 + SWZ(lr, kk * 32 + lg * 8)]);
                            // A = V^T rows (h), B = P^T cols (q)
                            oacc[n] = __builtin_amdgcn_mfma_f32_16x16x32_bf16(vf, pf, oacc[n], 0, 0, 0);
                        }
                    }
                }
            }
        }

        // epilogue: D[h_local=lg*4+r][q=lr] -> coalesced float4 stores
        const float rin = 1.0f / l;
        float* op = out + ((size_t)b * T_ + mt * 16 + lr) * H_;
        #pragma unroll
        for (int n = 0; n < 4; ++n) {
            float4 st;
            st.x = oacc[n][0] * rin;
            st.y = oacc[n][1] * rin;
            st.z = oacc[n][2] * rin;
            st.w = oacc[n][3] * rin;
            *reinterpret_cast<float4*>(op + n * 16 + lg * 4) = st;
        }
    }
}

extern "C" void kernel_launch(void* const* d_in, const int* in_sizes, int n_in,
                              void* d_out, int out_size, void* d_ws, size_t ws_size,
                              hipStream_t stream)
{
    (void)in_sizes; (void)n_in; (void)out_size;
    const float* x  = (const float*)d_in[0];
    const float* Wq = (const float*)d_in[1];
    const float* Wk = (const float*)d_in[2];
    const float* Wv = (const float*)d_in[3];
    float* o = (float*)d_out;

    if (ws_size >= (size_t)(WT3_TOTAL * sizeof(bf16))) {
        bf16* wt3 = (bf16*)d_ws;
        prep_wt3<<<dim3((WT3_TOTAL + 255) / 256), dim3(256), 0, stream>>>(Wq, Wk, Wv, wt3);
        head_fused12<1><<<dim3(B_), dim3(512), 0, stream>>>(x, Wq, Wk, Wv, wt3, o);
    } else {
        head_fused12<0><<<dim3(B_), dim3(512), 0, stream>>>(x, Wq, Wk, Wv, nullptr, o);
    }
}